// Round 13
// baseline (46.729 us; speedup 1.0000x reference)
//
#include <hip/hip_runtime.h>
#include <math.h>

#define DM 256   // d_model
#define NP 256   // n == m == 256 points
#define NH 4     // heads
#define DH 64    // dim per head

typedef unsigned long long u64;
typedef unsigned int u32;

// ---------------------------------------------------------------------------
// Kernel 1: qkv partial GEMM, split-K x2. 384 blocks.
// W staged in LDS (double-buffered); X read DIRECT from global (L2-resident,
// 4-way broadcast within wave) -- halves LDS-pipe demand vs R12.
// Outputs P[ks][mat][b][c][p] row-major [c][p]; consumers fold sum+bias.
// ---------------------------------------------------------------------------
__global__ __launch_bounds__(256) void qkv_part_kernel(
    const float* __restrict__ x, const float* __restrict__ src,
    const float* __restrict__ Wq, const float* __restrict__ Wk,
    const float* __restrict__ Wv,
    float* __restrict__ Ppart)
{
  const int tile = blockIdx.x;      // 16: 4x4 of 64x64 tiles
  const int mat  = blockIdx.y;      // 0=q,1=k,2=v
  const int bz   = blockIdx.z;      // b*2 + ks
  const int b  = bz >> 1;
  const int ks = bz & 1;
  const int tc = (tile >> 2) * 64;
  const int tp = (tile & 3) * 64;
  const float* W = (mat == 0) ? Wq : (mat == 1) ? Wk : Wv;
  const float* X = ((mat == 0) ? x : src) + (size_t)b * DM * NP;
  float* P = Ppart + ((size_t)((ks * 3 + mat) * 4 + b)) * 65536;

  __shared__ float Ws[2][32][64];
  const int tid = threadIdx.x;
  const int ty = tid >> 4, tx = tid & 15;
  const int c0 = tid >> 3;
  const int k4 = tid & 7;
  const int kbase = ks * 128;

  // thread's X column base (direct global reads in inner loop)
  const float* Xp = X + (size_t)kbase * NP + tp + tx * 4;

  float4 wA, wB;
  #define LOADW(K0)                                                            \
    wA = *(const float4*)&W[(size_t)(tc + c0)      * DM + (K0) + k4 * 4];      \
    wB = *(const float4*)&W[(size_t)(tc + c0 + 32) * DM + (K0) + k4 * 4];
  #define STOREW(BUF)                                                          \
    Ws[BUF][k4*4+0][c0] = wA.x; Ws[BUF][k4*4+1][c0] = wA.y;                    \
    Ws[BUF][k4*4+2][c0] = wA.z; Ws[BUF][k4*4+3][c0] = wA.w;                    \
    Ws[BUF][k4*4+0][c0+32] = wB.x; Ws[BUF][k4*4+1][c0+32] = wB.y;              \
    Ws[BUF][k4*4+2][c0+32] = wB.z; Ws[BUF][k4*4+3][c0+32] = wB.w;

  LOADW(kbase);
  STOREW(0);
  __syncthreads();

  float acc[4][4];
  #pragma unroll
  for (int i = 0; i < 4; ++i)
    #pragma unroll
    for (int j = 0; j < 4; ++j) acc[i][j] = 0.f;

  for (int ch = 0; ch < 4; ++ch) {          // K = 128 per block
    const int cur = ch & 1;
    if (ch < 3) { LOADW(kbase + (ch + 1) * 32); }
    #pragma unroll 8
    for (int kk = 0; kk < 32; ++kk) {
      const float4 a  = *(const float4*)&Ws[cur][kk][ty * 4];
      const float4 xv = *(const float4*)&Xp[(size_t)(ch * 32 + kk) * NP];
      const float av[4]  = {a.x, a.y, a.z, a.w};
      const float xvv[4] = {xv.x, xv.y, xv.z, xv.w};
      #pragma unroll
      for (int i = 0; i < 4; ++i)
        #pragma unroll
        for (int j = 0; j < 4; ++j) acc[i][j] += av[i] * xvv[j];
    }
    if (ch < 3) {
      __syncthreads();
      STOREW(cur ^ 1);
      __syncthreads();
    }
  }

  #pragma unroll
  for (int i = 0; i < 4; ++i) {
    float4 o4;
    o4.x = acc[i][0]; o4.y = acc[i][1]; o4.z = acc[i][2]; o4.w = acc[i][3];
    *(float4*)&P[(size_t)(tc + ty * 4 + i) * NP + tp + tx * 4] = o4;
  }
  #undef LOADW
  #undef STOREW
}

// ---------------------------------------------------------------------------
// Kernel 2: score GEMM (R12-proven); stages Q,K from split-K partials
// (sum+bias folded), merges this tile's 16 V rows -> Vt.
// ---------------------------------------------------------------------------
__global__ __launch_bounds__(256) void score_gemm_kernel(
    const float* __restrict__ Ppart,
    const float* __restrict__ bq, const float* __restrict__ bk,
    const float* __restrict__ bv,
    float* __restrict__ scores, float* __restrict__ Vt)
{
  const int tile = blockIdx.x;          // 16 = 4x4 tiles of 64x64
  const int bh   = blockIdx.y;          // 16
  const int tn = (tile >> 2) * 64;
  const int tm = (tile & 3) * 64;
  const int b = bh >> 2, h = bh & 3;

  const float* PQ0 = Ppart + ((size_t)( 0 + b)) * 65536;
  const float* PQ1 = Ppart + ((size_t)(12 + b)) * 65536;
  const float* PK0 = Ppart + ((size_t)( 4 + b)) * 65536;
  const float* PK1 = Ppart + ((size_t)(16 + b)) * 65536;
  const float* PV0 = Ppart + ((size_t)( 8 + b)) * 65536;
  const float* PV1 = Ppart + ((size_t)(20 + b)) * 65536;

  __shared__ float Qs[64][68];   // [d][n]
  __shared__ float Ks[64][68];   // [d][m]
  __shared__ float Vs[16][68];   // V-merge transpose tile [m][d]
  const int tid = threadIdx.x;

  #pragma unroll
  for (int pass = 0; pass < 4; ++pass) {
    const int u  = tid + pass * 256;
    const int pg = u & 15;
    const int d  = u >> 4;
    const int c  = d * 4 + h;
    const float bqv = bq[c], bkv = bk[c];
    const float4 q0 = *(const float4*)&PQ0[(size_t)c * NP + tn + pg * 4];
    const float4 q1 = *(const float4*)&PQ1[(size_t)c * NP + tn + pg * 4];
    const float4 k0 = *(const float4*)&PK0[(size_t)c * NP + tm + pg * 4];
    const float4 k1 = *(const float4*)&PK1[(size_t)c * NP + tm + pg * 4];
    Qs[d][pg*4+0] = q0.x + q1.x + bqv;
    Qs[d][pg*4+1] = q0.y + q1.y + bqv;
    Qs[d][pg*4+2] = q0.z + q1.z + bqv;
    Qs[d][pg*4+3] = q0.w + q1.w + bqv;
    Ks[d][pg*4+0] = k0.x + k1.x + bkv;
    Ks[d][pg*4+1] = k0.y + k1.y + bkv;
    Ks[d][pg*4+2] = k0.z + k1.z + bkv;
    Ks[d][pg*4+3] = k0.w + k1.w + bkv;
  }
  __syncthreads();

  const int ty = tid >> 4, tx = tid & 15;
  float acc[4][4];
  #pragma unroll
  for (int i = 0; i < 4; ++i)
    #pragma unroll
    for (int j = 0; j < 4; ++j) acc[i][j] = 0.f;

  #pragma unroll 4
  for (int d = 0; d < DH; ++d) {
    const float4 a  = *(const float4*)&Qs[d][ty * 4];
    const float4 bvv4 = *(const float4*)&Ks[d][tx * 4];
    const float av[4]  = {a.x, a.y, a.z, a.w};
    const float bvv[4] = {bvv4.x, bvv4.y, bvv4.z, bvv4.w};
    #pragma unroll
    for (int i = 0; i < 4; ++i)
      #pragma unroll
      for (int j = 0; j < 4; ++j) acc[i][j] += av[i] * bvv[j];
  }

  float* srow = scores + ((size_t)bh * NP + tn) * NP + tm;
  #pragma unroll
  for (int i = 0; i < 4; ++i) {
    float4 o4;
    o4.x = acc[i][0] * 0.125f; o4.y = acc[i][1] * 0.125f;
    o4.z = acc[i][2] * 0.125f; o4.w = acc[i][3] * 0.125f;
    *(float4*)&srow[(size_t)(ty * 4 + i) * NP + tx * 4] = o4;
  }

  // ---- V-merge side job: 16 m's (m = tile*16 .. +15) -----------------------
  {
    const int dV = tid >> 2;
    const int mg = tid & 3;
    const int cV = dV * 4 + h;
    const float bvb = bv[cV];
    const float4 v0 = *(const float4*)&PV0[(size_t)cV * NP + tile * 16 + mg * 4];
    const float4 v1 = *(const float4*)&PV1[(size_t)cV * NP + tile * 16 + mg * 4];
    Vs[mg*4+0][dV] = v0.x + v1.x + bvb;
    Vs[mg*4+1][dV] = v0.y + v1.y + bvb;
    Vs[mg*4+2][dV] = v0.z + v1.z + bvb;
    Vs[mg*4+3][dV] = v0.w + v1.w + bvb;
  }
  __syncthreads();
  {
    const int mrow = tid >> 4;
    const int dg   = tid & 15;
    const float4 o = *(const float4*)&Vs[mrow][dg * 4];
    *(float4*)&Vt[((size_t)bh * NP + tile * 16 + mrow) * DH + dg * 4] = o;
  }
}

// ---------------------------------------------------------------------------
// Kernel 3: ballot-radix top-k (R9-proven) + depth-8 two-phase gather.
// ---------------------------------------------------------------------------
__global__ __launch_bounds__(256) void attn_topk_kernel(
    const float* __restrict__ scores, const float* __restrict__ Vt,
    const float* __restrict__ x_pos, const float* __restrict__ src_pos,
    const float* __restrict__ lrf,
    const int* __restrict__ kptr,
    float* __restrict__ O)
{
  const int tid  = threadIdx.x;
  const int wid  = tid >> 6;
  const int lane = tid & 63;
  const int bidx = blockIdx.x;                      // 0..1023
  const int rb   = (bidx & 7) * 128 + (bidx >> 3);  // bijective XCD swizzle
  const int row  = rb * 4 + wid;
  const int n    = row & (NP - 1);
  const int bh   = row >> 8;
  const int b    = bh >> 2;
  const int h    = bh & 3;

  int kk = *kptr;
  if (kk > 64) kk = 64;
  if (kk < 1) kk = 1;

  __shared__ float  eslot[4][64];
  __shared__ alignas(16) int msel[4][64];
  __shared__ float4 ang[4][64];
  __shared__ float  otile[4][64];

  const float4 s4 = *(const float4*)&scores[(size_t)row * NP + lane * 4];
  float s[4] = { s4.x, s4.y, s4.z, s4.w };
  u32 u[4], lowv[4];
  #pragma unroll
  for (int r = 0; r < 4; ++r) {
    u32 bb = __float_as_uint(s[r]);
    u[r] = (bb & 0x80000000u) ? ~bb : (bb | 0x80000000u);
    lowv[r] = (u32)(255 - (lane * 4 + r));
  }

  // phase 1: T = value-bits of kth largest
  u32 T = 0u;
  #pragma unroll
  for (int bit = 31; bit >= 0; --bit) {
    const u32 cand = T | (1u << bit);
    int c = 0;
    #pragma unroll
    for (int r = 0; r < 4; ++r) c += __popcll(__ballot(u[r] >= cand));
    if (c >= kk) T = cand;
  }
  int c_gt = 0;
  #pragma unroll
  for (int r = 0; r < 4; ++r) c_gt += __popcll(__ballot(u[r] > T));

  // phase 2: tie-break threshold on low bits (255-m)
  u32 Lo = 0u;
  #pragma unroll
  for (int bit = 7; bit >= 0; --bit) {
    const u32 cand = Lo | (1u << bit);
    int c = c_gt;
    #pragma unroll
    for (int r = 0; r < 4; ++r)
      c += __popcll(__ballot((u[r] == T) && (lowv[r] >= cand)));
    if (c >= kk) Lo = cand;
  }

  // membership, e-values, Z
  const float sT = __uint_as_float((T & 0x80000000u) ? (T & 0x7fffffffu) : ~T);
  bool sel[4]; float e[4]; u64 selm[4];
  #pragma unroll
  for (int r = 0; r < 4; ++r) {
    sel[r] = (u[r] > T) || ((u[r] == T) && (lowv[r] >= Lo));
    e[r] = sel[r] ? expf(s[r] - sT) : 0.f;
    selm[r] = __ballot(sel[r]);
  }
  float z = e[0] + e[1] + e[2] + e[3];
  #pragma unroll
  for (int off = 32; off; off >>= 1) z += __shfl_xor(z, off);

  // compaction
  const u64 lt = (1ull << lane) - 1ull;
  int base = 0;
  #pragma unroll
  for (int r = 0; r < 4; ++r) {
    if (sel[r]) {
      const int slot = base + __popcll(selm[r] & lt);
      eslot[wid][slot] = e[r];
      msel[wid][slot]  = lane * 4 + r;
    }
    base += __popcll(selm[r]);
  }

  // lane j: rotary-angle coefficients for slot j (algebraic)
  if (lane < kk) {
    const float ej = eslot[wid][lane];
    const int   mj = msel[wid][lane];
    const float p = ej / z;
    const float* xp = x_pos   + ((size_t)b * NP + mj) * 3;
    const float* sp = src_pos + ((size_t)b * NP + n) * 3;
    const float* L  = lrf     + ((size_t)b * NP + mj) * 9;
    const float r0 = xp[0] - sp[0], r1 = xp[1] - sp[1], r2v = xp[2] - sp[2];
    const float px = L[0]*r0 + L[3]*r1 + L[6]*r2v;   // lrf^T r
    const float py = L[1]*r0 + L[4]*r1 + L[7]*r2v;
    const float pz = L[2]*r0 + L[5]*r1 + L[8]*r2v;
    const float r2 = px*px + py*py;
    const float inv2 = (r2 > 0.f) ? rsqrtf(r2) : 0.f;
    const float ca = (r2 > 0.f) ? px * inv2 : 1.f;
    const float sa = py * inv2;
    const float r2d = r2 * inv2;
    const float r3 = r2 + pz * pz;
    const float inv3 = (r3 > 0.f) ? rsqrtf(r3) : 0.f;
    const float cph = (r3 > 0.f) ? r2d * inv3 : 1.f;
    const float sph = pz * inv3;
    ang[wid][lane] = make_float4(p * ca, p * sa, p * cph, p * sph);
  }

  // gather: depth-8 two-phase (issue 8 loads, then consume), named scalars
  const float* vbase = Vt + (size_t)bh * NP * DH;
  const bool useA = ((lane & 3) < 2);
  const bool odd  = (lane & 1);
  const int  ev   = lane & ~1;
  float acc = 0.f;

  #define ACCSTEP(V2, A4) {                                                   \
    const float vm  = odd ? (V2).y :  (V2).x;                                 \
    const float dsc = odd ? (V2).x : -(V2).y;                                 \
    acc += vm  * (useA ? (A4).x : (A4).z)                                     \
         + dsc * (useA ? (A4).y : (A4).w); }

  int j = 0;
  for (; j + 8 <= kk; j += 8) {
    const int4 mA = *(const int4*)&msel[wid][j];
    const int4 mB = *(const int4*)&msel[wid][j + 4];
    const float2 v0 = *(const float2*)(vbase + (size_t)mA.x * DH + ev);
    const float2 v1 = *(const float2*)(vbase + (size_t)mA.y * DH + ev);
    const float2 v2 = *(const float2*)(vbase + (size_t)mA.z * DH + ev);
    const float2 v3 = *(const float2*)(vbase + (size_t)mA.w * DH + ev);
    const float2 v4 = *(const float2*)(vbase + (size_t)mB.x * DH + ev);
    const float2 v5 = *(const float2*)(vbase + (size_t)mB.y * DH + ev);
    const float2 v6 = *(const float2*)(vbase + (size_t)mB.z * DH + ev);
    const float2 v7 = *(const float2*)(vbase + (size_t)mB.w * DH + ev);
    const float4 A0 = ang[wid][j+0]; ACCSTEP(v0, A0);
    const float4 A1 = ang[wid][j+1]; ACCSTEP(v1, A1);
    const float4 A2 = ang[wid][j+2]; ACCSTEP(v2, A2);
    const float4 A3 = ang[wid][j+3]; ACCSTEP(v3, A3);
    const float4 A4 = ang[wid][j+4]; ACCSTEP(v4, A4);
    const float4 A5 = ang[wid][j+5]; ACCSTEP(v5, A5);
    const float4 A6 = ang[wid][j+6]; ACCSTEP(v6, A6);
    const float4 A7 = ang[wid][j+7]; ACCSTEP(v7, A7);
  }
  for (; j < kk; ++j) {
    const int m = msel[wid][j];
    const float2 vv = *(const float2*)(vbase + (size_t)m * DH + ev);
    const float4 A  = ang[wid][j];
    ACCSTEP(vv, A);
  }
  #undef ACCSTEP

  otile[wid][lane] = acc;
  __syncthreads();
  if (wid == 0) {
    float4 o4;
    o4.x = otile[0][lane]; o4.y = otile[1][lane];
    o4.z = otile[2][lane]; o4.w = otile[3][lane];
    const int c = (lane << 2) | h;
    const int n0 = (rb * 4) & (NP - 1);
    *(float4*)&O[((size_t)b * DM + c) * NP + n0] = o4;
  }
}

// ---------------------------------------------------------------------------
// Kernel 4: final projection partials, split-K x4. 256 blocks.
// W in LDS; X = O read direct from global (L2-resident).
// ---------------------------------------------------------------------------
__global__ __launch_bounds__(256) void final_part_kernel(
    const float* __restrict__ O, const float* __restrict__ Wm,
    float* __restrict__ Pf)
{
  const int tile = blockIdx.x;          // 16 = 4x4 of 64x64
  const int ks   = blockIdx.y;          // 4 K-slices of 64
  const int b    = blockIdx.z;
  const int tc = (tile >> 2) * 64;
  const int tp = (tile & 3) * 64;
  const float* X = O + (size_t)b * DM * NP;
  float* P = Pf + (size_t)ks * (DM * NP * 4) + (size_t)b * DM * NP;

  __shared__ float Ws[2][32][64];
  const int tid = threadIdx.x;
  const int ty = tid >> 4, tx = tid & 15;
  const int c0 = tid >> 3;
  const int k4 = tid & 7;
  const int kbase = ks * 64;

  const float* Xp = X + (size_t)kbase * NP + tp + tx * 4;

  float4 wA, wB;
  #define LOADW(K0)                                                            \
    wA = *(const float4*)&Wm[(size_t)(tc + c0)      * DM + (K0) + k4 * 4];     \
    wB = *(const float4*)&Wm[(size_t)(tc + c0 + 32) * DM + (K0) + k4 * 4];
  #define STOREW(BUF)                                                          \
    Ws[BUF][k4*4+0][c0] = wA.x; Ws[BUF][k4*4+1][c0] = wA.y;                    \
    Ws[BUF][k4*4+2][c0] = wA.z; Ws[BUF][k4*4+3][c0] = wA.w;                    \
    Ws[BUF][k4*4+0][c0+32] = wB.x; Ws[BUF][k4*4+1][c0+32] = wB.y;              \
    Ws[BUF][k4*4+2][c0+32] = wB.z; Ws[BUF][k4*4+3][c0+32] = wB.w;

  LOADW(kbase);
  STOREW(0);
  __syncthreads();

  float acc[4][4];
  #pragma unroll
  for (int i = 0; i < 4; ++i)
    #pragma unroll
    for (int j = 0; j < 4; ++j) acc[i][j] = 0.f;

  for (int ch = 0; ch < 2; ++ch) {          // K = 64 per block
    const int cur = ch & 1;
    if (ch < 1) { LOADW(kbase + 32); }
    #pragma unroll 8
    for (int kk = 0; kk < 32; ++kk) {
      const float4 a  = *(const float4*)&Ws[cur][kk][ty * 4];
      const float4 xv = *(const float4*)&Xp[(size_t)(ch * 32 + kk) * NP];
      const float av[4]  = {a.x, a.y, a.z, a.w};
      const float xvv[4] = {xv.x, xv.y, xv.z, xv.w};
      #pragma unroll
      for (int i = 0; i < 4; ++i)
        #pragma unroll
        for (int j = 0; j < 4; ++j) acc[i][j] += av[i] * xvv[j];
    }
    if (ch < 1) {
      __syncthreads();
      STOREW(cur ^ 1);
      __syncthreads();
    }
  }

  #pragma unroll
  for (int i = 0; i < 4; ++i) {
    float4 o4;
    o4.x = acc[i][0]; o4.y = acc[i][1]; o4.z = acc[i][2]; o4.w = acc[i][3];
    *(float4*)&P[(size_t)(tc + ty * 4 + i) * NP + tp + tx * 4] = o4;
  }
  #undef LOADW
  #undef STOREW
}

// ---------------------------------------------------------------------------
// Kernel 5: merge final partials + bias -> out. (R12-proven)
// ---------------------------------------------------------------------------
__global__ __launch_bounds__(256) void final_merge_kernel(
    const float* __restrict__ Pf, const float* __restrict__ bm,
    float* __restrict__ out)
{
  const int u = blockIdx.x * 256 + threadIdx.x;   // 65536 float4 units
  const int c = (u >> 6) & 255;
  const float bb = bm[c];
  const size_t stride = (size_t)DM * NP * 4 / 4;
  const float4* P4 = (const float4*)Pf;
  float4 a = P4[u];
  float4 b2 = P4[u + stride];
  float4 c2 = P4[u + 2 * stride];
  float4 d2 = P4[u + 3 * stride];
  float4 o;
  o.x = a.x + b2.x + c2.x + d2.x + bb;
  o.y = a.y + b2.y + c2.y + d2.y + bb;
  o.z = a.z + b2.z + c2.z + d2.z + bb;
  o.w = a.w + b2.w + c2.w + d2.w + bb;
  ((float4*)out)[u] = o;
}

// ---------------------------------------------------------------------------
extern "C" void kernel_launch(void* const* d_in, const int* in_sizes, int n_in,
                              void* d_out, int out_size, void* d_ws, size_t ws_size,
                              hipStream_t stream)
{
  const float* x       = (const float*)d_in[0];
  const float* source  = (const float*)d_in[1];
  const float* x_pos   = (const float*)d_in[2];
  const float* src_pos = (const float*)d_in[3];
  const float* lrf     = (const float*)d_in[4];
  const float* Wq = (const float*)d_in[5];
  const float* bq = (const float*)d_in[6];
  const float* Wk = (const float*)d_in[7];
  const float* bk = (const float*)d_in[8];
  const float* Wv = (const float*)d_in[9];
  const float* bv = (const float*)d_in[10];
  const float* Wm = (const float*)d_in[11];
  const float* bm = (const float*)d_in[12];
  const int* kptr = (const int*)d_in[13];
  float* out = (float*)d_out;

  // workspace layout (floats)
  float* ws = (float*)d_ws;
  float* Ppart  = ws;                     // [2ks][3mat][4b][256][256] = 1572864
  float* scores = Ppart + 1572864;        // [16][256][256] = 1048576
  float* Vt     = scores + 1048576;       // [16][256][64]  = 262144
  float* O      = Vt + 262144;            // [4][256][256]  = 262144
  float* Pf     = O + 262144;             // [4ks][4b][256][256] = 1048576
  // total ~16 MB

  qkv_part_kernel<<<dim3(16, 3, 8), 256, 0, stream>>>(
      x, source, Wq, Wk, Wv, Ppart);
  score_gemm_kernel<<<dim3(16, 16), 256, 0, stream>>>(
      Ppart, bq, bk, bv, scores, Vt);
  attn_topk_kernel<<<dim3(1024), 256, 0, stream>>>(
      scores, Vt, x_pos, src_pos, lrf, kptr, O);
  final_part_kernel<<<dim3(16, 4, 4), 256, 0, stream>>>(
      O, Wm, Pf);
  final_merge_kernel<<<dim3(256), 256, 0, stream>>>(
      Pf, bm, out);
}

// Round 14
// 42.860 us; speedup vs baseline: 1.0903x; 1.0903x over previous
//
#include <hip/hip_runtime.h>
#include <math.h>

#define DM 256   // d_model
#define NP 256   // n == m == 256 points
#define NH 4     // heads
#define DH 64    // dim per head

typedef unsigned long long u64;
typedef unsigned int u32;

// ---------------------------------------------------------------------------
// Kernel 1: qkv partial GEMM, split-K x4. 768 blocks (= 3/CU, balanced).
// R12-proven LDS-staged body, K = 64 per block (2 chunks, double-buffered).
// Outputs P[ks][mat][b][c][p] row-major [c][p]; consumers fold sum+bias.
// ---------------------------------------------------------------------------
__global__ __launch_bounds__(256) void qkv_part_kernel(
    const float* __restrict__ x, const float* __restrict__ src,
    const float* __restrict__ Wq, const float* __restrict__ Wk,
    const float* __restrict__ Wv,
    float* __restrict__ Ppart)
{
  const int tile = blockIdx.x;      // 16: 4x4 of 64x64 tiles
  const int mat  = blockIdx.y;      // 0=q,1=k,2=v
  const int bz   = blockIdx.z;      // b*4 + ks
  const int b  = bz >> 2;
  const int ks = bz & 3;
  const int tc = (tile >> 2) * 64;
  const int tp = (tile & 3) * 64;
  const float* W = (mat == 0) ? Wq : (mat == 1) ? Wk : Wv;
  const float* X = ((mat == 0) ? x : src) + (size_t)b * DM * NP;
  float* P = Ppart + ((size_t)((ks * 3 + mat) * 4 + b)) * 65536;

  __shared__ float Ws[2][32][64];
  __shared__ float Xs[2][32][64];
  const int tid = threadIdx.x;
  const int ty = tid >> 4, tx = tid & 15;
  const int c0 = tid >> 3;
  const int k4 = tid & 7;
  const int pX = tid & 15;
  const int kX = tid >> 4;
  const int kbase = ks * 64;

  float4 wA, wB, xA, xB;
  #define LOADQKV(K0)                                                          \
    wA = *(const float4*)&W[(size_t)(tc + c0)      * DM + (K0) + k4 * 4];      \
    wB = *(const float4*)&W[(size_t)(tc + c0 + 32) * DM + (K0) + k4 * 4];      \
    xA = *(const float4*)&X[(size_t)((K0) + kX)      * NP + tp + pX * 4];      \
    xB = *(const float4*)&X[(size_t)((K0) + kX + 16) * NP + tp + pX * 4];

  #define STOREQKV(BUF)                                                        \
    Ws[BUF][k4*4+0][c0] = wA.x; Ws[BUF][k4*4+1][c0] = wA.y;                    \
    Ws[BUF][k4*4+2][c0] = wA.z; Ws[BUF][k4*4+3][c0] = wA.w;                    \
    Ws[BUF][k4*4+0][c0+32] = wB.x; Ws[BUF][k4*4+1][c0+32] = wB.y;              \
    Ws[BUF][k4*4+2][c0+32] = wB.z; Ws[BUF][k4*4+3][c0+32] = wB.w;              \
    *(float4*)&Xs[BUF][kX][pX*4]      = xA;                                    \
    *(float4*)&Xs[BUF][kX+16][pX*4]   = xB;

  LOADQKV(kbase);
  STOREQKV(0);
  __syncthreads();

  float acc[4][4];
  #pragma unroll
  for (int i = 0; i < 4; ++i)
    #pragma unroll
    for (int j = 0; j < 4; ++j) acc[i][j] = 0.f;

  for (int ch = 0; ch < 2; ++ch) {          // K = 64 per block
    const int cur = ch & 1;
    if (ch < 1) { LOADQKV(kbase + 32); }
    #pragma unroll
    for (int kk = 0; kk < 32; ++kk) {
      float4 a = *(const float4*)&Ws[cur][kk][ty * 4];
      float4 xv = *(const float4*)&Xs[cur][kk][tx * 4];
      float av[4] = {a.x, a.y, a.z, a.w};
      float xvv[4] = {xv.x, xv.y, xv.z, xv.w};
      #pragma unroll
      for (int i = 0; i < 4; ++i)
        #pragma unroll
        for (int j = 0; j < 4; ++j) acc[i][j] += av[i] * xvv[j];
    }
    if (ch < 1) {
      STOREQKV(cur ^ 1);
      __syncthreads();
    }
  }

  #pragma unroll
  for (int i = 0; i < 4; ++i) {
    float4 o4;
    o4.x = acc[i][0]; o4.y = acc[i][1]; o4.z = acc[i][2]; o4.w = acc[i][3];
    *(float4*)&P[(size_t)(tc + ty * 4 + i) * NP + tp + tx * 4] = o4;
  }
  #undef LOADQKV
  #undef STOREQKV
}

// ---------------------------------------------------------------------------
// Kernel 2: score GEMM; stages Q,K from 4 split-K partials (sum+bias folded),
// R12-proven GEMM body; merges this tile's 16 V rows -> Vt.
// ---------------------------------------------------------------------------
__global__ __launch_bounds__(256) void score_gemm_kernel(
    const float* __restrict__ Ppart,
    const float* __restrict__ bq, const float* __restrict__ bk,
    const float* __restrict__ bv,
    float* __restrict__ scores, float* __restrict__ Vt)
{
  const int tile = blockIdx.x;          // 16 = 4x4 tiles of 64x64
  const int bh   = blockIdx.y;          // 16
  const int tn = (tile >> 2) * 64;
  const int tm = (tile & 3) * 64;
  const int b = bh >> 2, h = bh & 3;

  // partial buffers: index (ks*3+mat)*4+b
  #define PBUF(KS, MAT) (Ppart + ((size_t)(((KS) * 3 + (MAT)) * 4 + b)) * 65536)

  __shared__ float Qs[64][68];   // [d][n]
  __shared__ float Ks[64][68];   // [d][m]
  __shared__ float Vs[16][68];   // V-merge transpose tile [m][d]
  const int tid = threadIdx.x;

  #pragma unroll
  for (int pass = 0; pass < 4; ++pass) {
    const int u  = tid + pass * 256;
    const int pg = u & 15;
    const int d  = u >> 4;
    const int c  = d * 4 + h;
    const float bqv = bq[c], bkv = bk[c];
    float qx = bqv, qy = bqv, qz = bqv, qw = bqv;
    float kx = bkv, ky = bkv, kz = bkv, kw = bkv;
    #pragma unroll
    for (int ksI = 0; ksI < 4; ++ksI) {
      const float4 q = *(const float4*)&PBUF(ksI, 0)[(size_t)c * NP + tn + pg * 4];
      const float4 k = *(const float4*)&PBUF(ksI, 1)[(size_t)c * NP + tm + pg * 4];
      qx += q.x; qy += q.y; qz += q.z; qw += q.w;
      kx += k.x; ky += k.y; kz += k.z; kw += k.w;
    }
    Qs[d][pg*4+0] = qx; Qs[d][pg*4+1] = qy;
    Qs[d][pg*4+2] = qz; Qs[d][pg*4+3] = qw;
    Ks[d][pg*4+0] = kx; Ks[d][pg*4+1] = ky;
    Ks[d][pg*4+2] = kz; Ks[d][pg*4+3] = kw;
  }
  __syncthreads();

  const int ty = tid >> 4, tx = tid & 15;
  float acc[4][4];
  #pragma unroll
  for (int i = 0; i < 4; ++i)
    #pragma unroll
    for (int j = 0; j < 4; ++j) acc[i][j] = 0.f;

  #pragma unroll 4
  for (int d = 0; d < DH; ++d) {
    const float4 a  = *(const float4*)&Qs[d][ty * 4];
    const float4 bvv4 = *(const float4*)&Ks[d][tx * 4];
    const float av[4]  = {a.x, a.y, a.z, a.w};
    const float bvv[4] = {bvv4.x, bvv4.y, bvv4.z, bvv4.w};
    #pragma unroll
    for (int i = 0; i < 4; ++i)
      #pragma unroll
      for (int j = 0; j < 4; ++j) acc[i][j] += av[i] * bvv[j];
  }

  float* srow = scores + ((size_t)bh * NP + tn) * NP + tm;
  #pragma unroll
  for (int i = 0; i < 4; ++i) {
    float4 o4;
    o4.x = acc[i][0] * 0.125f; o4.y = acc[i][1] * 0.125f;
    o4.z = acc[i][2] * 0.125f; o4.w = acc[i][3] * 0.125f;
    *(float4*)&srow[(size_t)(ty * 4 + i) * NP + tx * 4] = o4;
  }

  // ---- V-merge side job: 16 m's (m = tile*16 .. +15) -----------------------
  {
    const int dV = tid >> 2;
    const int mg = tid & 3;
    const int cV = dV * 4 + h;
    float vx = bv[cV], vy = vx, vz = vx, vw = vx;
    #pragma unroll
    for (int ksI = 0; ksI < 4; ++ksI) {
      const float4 v = *(const float4*)&PBUF(ksI, 2)[(size_t)cV * NP + tile * 16 + mg * 4];
      vx += v.x; vy += v.y; vz += v.z; vw += v.w;
    }
    Vs[mg*4+0][dV] = vx;
    Vs[mg*4+1][dV] = vy;
    Vs[mg*4+2][dV] = vz;
    Vs[mg*4+3][dV] = vw;
  }
  __syncthreads();
  {
    const int mrow = tid >> 4;
    const int dg   = tid & 15;
    const float4 o = *(const float4*)&Vs[mrow][dg * 4];
    *(float4*)&Vt[((size_t)bh * NP + tile * 16 + mrow) * DH + dg * 4] = o;
  }
  #undef PBUF
}

// ---------------------------------------------------------------------------
// Kernel 3: ballot-radix top-k (R9-proven) + prefetch-4 gather (R12-proven).
// ---------------------------------------------------------------------------
__global__ __launch_bounds__(256) void attn_topk_kernel(
    const float* __restrict__ scores, const float* __restrict__ Vt,
    const float* __restrict__ x_pos, const float* __restrict__ src_pos,
    const float* __restrict__ lrf,
    const int* __restrict__ kptr,
    float* __restrict__ O)
{
  const int tid  = threadIdx.x;
  const int wid  = tid >> 6;
  const int lane = tid & 63;
  const int bidx = blockIdx.x;                      // 0..1023
  const int rb   = (bidx & 7) * 128 + (bidx >> 3);  // bijective XCD swizzle
  const int row  = rb * 4 + wid;
  const int n    = row & (NP - 1);
  const int bh   = row >> 8;
  const int b    = bh >> 2;
  const int h    = bh & 3;

  int kk = *kptr;
  if (kk > 64) kk = 64;
  if (kk < 1) kk = 1;

  __shared__ float  eslot[4][64];
  __shared__ int    msel[4][64];
  __shared__ float4 ang[4][64];
  __shared__ float  otile[4][64];

  const float4 s4 = *(const float4*)&scores[(size_t)row * NP + lane * 4];
  float s[4] = { s4.x, s4.y, s4.z, s4.w };
  u32 u[4], lowv[4];
  #pragma unroll
  for (int r = 0; r < 4; ++r) {
    u32 bb = __float_as_uint(s[r]);
    u[r] = (bb & 0x80000000u) ? ~bb : (bb | 0x80000000u);
    lowv[r] = (u32)(255 - (lane * 4 + r));
  }

  // phase 1: T = value-bits of kth largest
  u32 T = 0u;
  #pragma unroll
  for (int bit = 31; bit >= 0; --bit) {
    const u32 cand = T | (1u << bit);
    int c = 0;
    #pragma unroll
    for (int r = 0; r < 4; ++r) c += __popcll(__ballot(u[r] >= cand));
    if (c >= kk) T = cand;
  }
  int c_gt = 0;
  #pragma unroll
  for (int r = 0; r < 4; ++r) c_gt += __popcll(__ballot(u[r] > T));

  // phase 2: tie-break threshold on low bits (255-m)
  u32 Lo = 0u;
  #pragma unroll
  for (int bit = 7; bit >= 0; --bit) {
    const u32 cand = Lo | (1u << bit);
    int c = c_gt;
    #pragma unroll
    for (int r = 0; r < 4; ++r)
      c += __popcll(__ballot((u[r] == T) && (lowv[r] >= cand)));
    if (c >= kk) Lo = cand;
  }

  // membership, e-values, Z
  const float sT = __uint_as_float((T & 0x80000000u) ? (T & 0x7fffffffu) : ~T);
  bool sel[4]; float e[4]; u64 selm[4];
  #pragma unroll
  for (int r = 0; r < 4; ++r) {
    sel[r] = (u[r] > T) || ((u[r] == T) && (lowv[r] >= Lo));
    e[r] = sel[r] ? __expf(s[r] - sT) : 0.f;
    selm[r] = __ballot(sel[r]);
  }
  float z = e[0] + e[1] + e[2] + e[3];
  #pragma unroll
  for (int off = 32; off; off >>= 1) z += __shfl_xor(z, off);

  // compaction
  const u64 lt = (1ull << lane) - 1ull;
  int base = 0;
  #pragma unroll
  for (int r = 0; r < 4; ++r) {
    if (sel[r]) {
      const int slot = base + __popcll(selm[r] & lt);
      eslot[wid][slot] = e[r];
      msel[wid][slot]  = lane * 4 + r;
    }
    base += __popcll(selm[r]);
  }

  // lane j: rotary-angle coefficients for slot j (algebraic)
  if (lane < kk) {
    const float ej = eslot[wid][lane];
    const int   mj = msel[wid][lane];
    const float p = ej / z;
    const float* xp = x_pos   + ((size_t)b * NP + mj) * 3;
    const float* sp = src_pos + ((size_t)b * NP + n) * 3;
    const float* L  = lrf     + ((size_t)b * NP + mj) * 9;
    const float r0 = xp[0] - sp[0], r1 = xp[1] - sp[1], r2v = xp[2] - sp[2];
    const float px = L[0]*r0 + L[3]*r1 + L[6]*r2v;   // lrf^T r
    const float py = L[1]*r0 + L[4]*r1 + L[7]*r2v;
    const float pz = L[2]*r0 + L[5]*r1 + L[8]*r2v;
    const float r2 = px*px + py*py;
    const float inv2 = (r2 > 0.f) ? rsqrtf(r2) : 0.f;
    const float ca = (r2 > 0.f) ? px * inv2 : 1.f;
    const float sa = py * inv2;
    const float r2d = r2 * inv2;
    const float r3 = r2 + pz * pz;
    const float inv3 = (r3 > 0.f) ? rsqrtf(r3) : 0.f;
    const float cph = (r3 > 0.f) ? r2d * inv3 : 1.f;
    const float sph = pz * inv3;
    ang[wid][lane] = make_float4(p * ca, p * sa, p * cph, p * sph);
  }

  // gather: 2-stage software pipeline (prefetch next 4 V-float2s)
  const float* vbase = Vt + (size_t)bh * NP * DH;
  const bool useA = ((lane & 3) < 2);
  const bool odd  = (lane & 1);
  const int  ev   = lane & ~1;
  float acc = 0.f;

  #define ACCSTEP(V2, A4) {                                                   \
    const float vm  = odd ? (V2).y :  (V2).x;                                 \
    const float dsc = odd ? (V2).x : -(V2).y;                                 \
    acc += vm  * (useA ? (A4).x : (A4).z)                                     \
         + dsc * (useA ? (A4).y : (A4).w); }

  int j = 0;
  float2 v0, v1, v2, v3;
  if (kk >= 4) {
    const int a0 = msel[wid][0], a1 = msel[wid][1];
    const int a2 = msel[wid][2], a3 = msel[wid][3];
    v0 = *(const float2*)(vbase + (size_t)a0 * DH + ev);
    v1 = *(const float2*)(vbase + (size_t)a1 * DH + ev);
    v2 = *(const float2*)(vbase + (size_t)a2 * DH + ev);
    v3 = *(const float2*)(vbase + (size_t)a3 * DH + ev);
  }
  for (; j + 8 <= kk; j += 4) {
    const int n0 = msel[wid][j+4], n1 = msel[wid][j+5];
    const int n2 = msel[wid][j+6], n3 = msel[wid][j+7];
    const float2 w0 = *(const float2*)(vbase + (size_t)n0 * DH + ev);
    const float2 w1 = *(const float2*)(vbase + (size_t)n1 * DH + ev);
    const float2 w2 = *(const float2*)(vbase + (size_t)n2 * DH + ev);
    const float2 w3 = *(const float2*)(vbase + (size_t)n3 * DH + ev);
    const float4 A0 = ang[wid][j],   A1 = ang[wid][j+1];
    const float4 A2 = ang[wid][j+2], A3 = ang[wid][j+3];
    ACCSTEP(v0, A0); ACCSTEP(v1, A1); ACCSTEP(v2, A2); ACCSTEP(v3, A3);
    v0 = w0; v1 = w1; v2 = w2; v3 = w3;
  }
  if (j + 4 <= kk) {
    const float4 A0 = ang[wid][j],   A1 = ang[wid][j+1];
    const float4 A2 = ang[wid][j+2], A3 = ang[wid][j+3];
    ACCSTEP(v0, A0); ACCSTEP(v1, A1); ACCSTEP(v2, A2); ACCSTEP(v3, A3);
    j += 4;
  }
  for (; j < kk; ++j) {
    const int m = msel[wid][j];
    const float2 vv = *(const float2*)(vbase + (size_t)m * DH + ev);
    const float4 A  = ang[wid][j];
    ACCSTEP(vv, A);
  }
  #undef ACCSTEP

  otile[wid][lane] = acc;
  __syncthreads();
  if (wid == 0) {
    float4 o4;
    o4.x = otile[0][lane]; o4.y = otile[1][lane];
    o4.z = otile[2][lane]; o4.w = otile[3][lane];
    const int c = (lane << 2) | h;
    const int n0 = (rb * 4) & (NP - 1);
    *(float4*)&O[((size_t)b * DM + c) * NP + n0] = o4;
  }
}

// ---------------------------------------------------------------------------
// Kernel 4: final projection partials, split-K x4. 256 blocks (1/CU).
// R12-proven LDS-staged body.
// ---------------------------------------------------------------------------
__global__ __launch_bounds__(256) void final_part_kernel(
    const float* __restrict__ O, const float* __restrict__ Wm,
    float* __restrict__ Pf)
{
  const int tile = blockIdx.x;          // 16 = 4x4 of 64x64
  const int ks   = blockIdx.y;          // 4 K-slices of 64
  const int b    = blockIdx.z;
  const int tc = (tile >> 2) * 64;
  const int tp = (tile & 3) * 64;
  const float* X = O + (size_t)b * DM * NP;
  float* P = Pf + (size_t)ks * (DM * NP * 4) + (size_t)b * DM * NP;

  __shared__ float Ws[2][32][64];
  __shared__ float Xs[2][32][64];
  const int tid = threadIdx.x;
  const int ty = tid >> 4, tx = tid & 15;
  const int c0 = tid >> 3;
  const int k4 = tid & 7;
  const int pX = tid & 15;
  const int kX = tid >> 4;
  const int kbase = ks * 64;

  float4 wA, wB, xA, xB;
  #define LOADF(K0)                                                            \
    wA = *(const float4*)&Wm[(size_t)(tc + c0)      * DM + (K0) + k4 * 4];     \
    wB = *(const float4*)&Wm[(size_t)(tc + c0 + 32) * DM + (K0) + k4 * 4];     \
    xA = *(const float4*)&X[(size_t)((K0) + kX)      * NP + tp + pX * 4];      \
    xB = *(const float4*)&X[(size_t)((K0) + kX + 16) * NP + tp + pX * 4];

  #define STOREF(BUF)                                                          \
    Ws[BUF][k4*4+0][c0] = wA.x; Ws[BUF][k4*4+1][c0] = wA.y;                    \
    Ws[BUF][k4*4+2][c0] = wA.z; Ws[BUF][k4*4+3][c0] = wA.w;                    \
    Ws[BUF][k4*4+0][c0+32] = wB.x; Ws[BUF][k4*4+1][c0+32] = wB.y;              \
    Ws[BUF][k4*4+2][c0+32] = wB.z; Ws[BUF][k4*4+3][c0+32] = wB.w;              \
    *(float4*)&Xs[BUF][kX][pX*4]      = xA;                                    \
    *(float4*)&Xs[BUF][kX+16][pX*4]   = xB;

  LOADF(kbase);
  STOREF(0);
  __syncthreads();

  float acc[4][4];
  #pragma unroll
  for (int i = 0; i < 4; ++i)
    #pragma unroll
    for (int j = 0; j < 4; ++j) acc[i][j] = 0.f;

  for (int ch = 0; ch < 2; ++ch) {          // K = 64 per block
    const int cur = ch & 1;
    if (ch < 1) { LOADF(kbase + 32); }
    #pragma unroll
    for (int kk = 0; kk < 32; ++kk) {
      float4 a = *(const float4*)&Ws[cur][kk][ty * 4];
      float4 xv = *(const float4*)&Xs[cur][kk][tx * 4];
      float av[4] = {a.x, a.y, a.z, a.w};
      float xvv[4] = {xv.x, xv.y, xv.z, xv.w};
      #pragma unroll
      for (int i = 0; i < 4; ++i)
        #pragma unroll
        for (int j = 0; j < 4; ++j) acc[i][j] += av[i] * xvv[j];
    }
    if (ch < 1) {
      STOREF(cur ^ 1);
      __syncthreads();
    }
  }

  #pragma unroll
  for (int i = 0; i < 4; ++i) {
    float4 o4;
    o4.x = acc[i][0]; o4.y = acc[i][1]; o4.z = acc[i][2]; o4.w = acc[i][3];
    *(float4*)&P[(size_t)(tc + ty * 4 + i) * NP + tp + tx * 4] = o4;
  }
  #undef LOADF
  #undef STOREF
}

// ---------------------------------------------------------------------------
// Kernel 5: merge final partials + bias -> out. (R12-proven)
// ---------------------------------------------------------------------------
__global__ __launch_bounds__(256) void final_merge_kernel(
    const float* __restrict__ Pf, const float* __restrict__ bm,
    float* __restrict__ out)
{
  const int u = blockIdx.x * 256 + threadIdx.x;   // 65536 float4 units
  const int c = (u >> 6) & 255;
  const float bb = bm[c];
  const size_t stride = (size_t)DM * NP * 4 / 4;
  const float4* P4 = (const float4*)Pf;
  float4 a = P4[u];
  float4 b2 = P4[u + stride];
  float4 c2 = P4[u + 2 * stride];
  float4 d2 = P4[u + 3 * stride];
  float4 o;
  o.x = a.x + b2.x + c2.x + d2.x + bb;
  o.y = a.y + b2.y + c2.y + d2.y + bb;
  o.z = a.z + b2.z + c2.z + d2.z + bb;
  o.w = a.w + b2.w + c2.w + d2.w + bb;
  ((float4*)out)[u] = o;
}

// ---------------------------------------------------------------------------
extern "C" void kernel_launch(void* const* d_in, const int* in_sizes, int n_in,
                              void* d_out, int out_size, void* d_ws, size_t ws_size,
                              hipStream_t stream)
{
  const float* x       = (const float*)d_in[0];
  const float* source  = (const float*)d_in[1];
  const float* x_pos   = (const float*)d_in[2];
  const float* src_pos = (const float*)d_in[3];
  const float* lrf     = (const float*)d_in[4];
  const float* Wq = (const float*)d_in[5];
  const float* bq = (const float*)d_in[6];
  const float* Wk = (const float*)d_in[7];
  const float* bk = (const float*)d_in[8];
  const float* Wv = (const float*)d_in[9];
  const float* bv = (const float*)d_in[10];
  const float* Wm = (const float*)d_in[11];
  const float* bm = (const float*)d_in[12];
  const int* kptr = (const int*)d_in[13];
  float* out = (float*)d_out;

  // workspace layout (floats)
  float* ws = (float*)d_ws;
  float* Ppart  = ws;                     // [4ks][3mat][4b][256][256] = 3145728
  float* scores = Ppart + 3145728;        // [16][256][256] = 1048576
  float* Vt     = scores + 1048576;       // [16][256][64]  = 262144
  float* O      = Vt + 262144;            // [4][256][256]  = 262144
  float* Pf     = O + 262144;             // [4ks][4b][256][256] = 1048576
  // total ~23 MB

  qkv_part_kernel<<<dim3(16, 3, 16), 256, 0, stream>>>(
      x, source, Wq, Wk, Wv, Ppart);
  score_gemm_kernel<<<dim3(16, 16), 256, 0, stream>>>(
      Ppart, bq, bk, bv, scores, Vt);
  attn_topk_kernel<<<dim3(1024), 256, 0, stream>>>(
      scores, Vt, x_pos, src_pos, lrf, kptr, O);
  final_part_kernel<<<dim3(16, 4, 4), 256, 0, stream>>>(
      O, Wm, Pf);
  final_merge_kernel<<<dim3(256), 256, 0, stream>>>(
      Pf, bm, out);
}

// Round 15
// 42.559 us; speedup vs baseline: 1.0980x; 1.0071x over previous
//
#include <hip/hip_runtime.h>
#include <math.h>

#define DM 256   // d_model
#define NP 256   // n == m == 256 points
#define NH 4     // heads
#define DH 64    // dim per head

typedef unsigned long long u64;
typedef unsigned int u32;

// ---------------------------------------------------------------------------
// Kernel 1: qkv partial GEMM, split-K x4. 768 blocks (= 3/CU). (R14-proven)
// ---------------------------------------------------------------------------
__global__ __launch_bounds__(256) void qkv_part_kernel(
    const float* __restrict__ x, const float* __restrict__ src,
    const float* __restrict__ Wq, const float* __restrict__ Wk,
    const float* __restrict__ Wv,
    float* __restrict__ Ppart)
{
  const int tile = blockIdx.x;      // 16: 4x4 of 64x64 tiles
  const int mat  = blockIdx.y;      // 0=q,1=k,2=v
  const int bz   = blockIdx.z;      // b*4 + ks
  const int b  = bz >> 2;
  const int ks = bz & 3;
  const int tc = (tile >> 2) * 64;
  const int tp = (tile & 3) * 64;
  const float* W = (mat == 0) ? Wq : (mat == 1) ? Wk : Wv;
  const float* X = ((mat == 0) ? x : src) + (size_t)b * DM * NP;
  float* P = Ppart + ((size_t)((ks * 3 + mat) * 4 + b)) * 65536;

  __shared__ float Ws[2][32][64];
  __shared__ float Xs[2][32][64];
  const int tid = threadIdx.x;
  const int ty = tid >> 4, tx = tid & 15;
  const int c0 = tid >> 3;
  const int k4 = tid & 7;
  const int pX = tid & 15;
  const int kX = tid >> 4;
  const int kbase = ks * 64;

  float4 wA, wB, xA, xB;
  #define LOADQKV(K0)                                                          \
    wA = *(const float4*)&W[(size_t)(tc + c0)      * DM + (K0) + k4 * 4];      \
    wB = *(const float4*)&W[(size_t)(tc + c0 + 32) * DM + (K0) + k4 * 4];      \
    xA = *(const float4*)&X[(size_t)((K0) + kX)      * NP + tp + pX * 4];      \
    xB = *(const float4*)&X[(size_t)((K0) + kX + 16) * NP + tp + pX * 4];

  #define STOREQKV(BUF)                                                        \
    Ws[BUF][k4*4+0][c0] = wA.x; Ws[BUF][k4*4+1][c0] = wA.y;                    \
    Ws[BUF][k4*4+2][c0] = wA.z; Ws[BUF][k4*4+3][c0] = wA.w;                    \
    Ws[BUF][k4*4+0][c0+32] = wB.x; Ws[BUF][k4*4+1][c0+32] = wB.y;              \
    Ws[BUF][k4*4+2][c0+32] = wB.z; Ws[BUF][k4*4+3][c0+32] = wB.w;              \
    *(float4*)&Xs[BUF][kX][pX*4]      = xA;                                    \
    *(float4*)&Xs[BUF][kX+16][pX*4]   = xB;

  LOADQKV(kbase);
  STOREQKV(0);
  __syncthreads();

  float acc[4][4];
  #pragma unroll
  for (int i = 0; i < 4; ++i)
    #pragma unroll
    for (int j = 0; j < 4; ++j) acc[i][j] = 0.f;

  for (int ch = 0; ch < 2; ++ch) {          // K = 64 per block
    const int cur = ch & 1;
    if (ch < 1) { LOADQKV(kbase + 32); }
    #pragma unroll
    for (int kk = 0; kk < 32; ++kk) {
      float4 a = *(const float4*)&Ws[cur][kk][ty * 4];
      float4 xv = *(const float4*)&Xs[cur][kk][tx * 4];
      float av[4] = {a.x, a.y, a.z, a.w};
      float xvv[4] = {xv.x, xv.y, xv.z, xv.w};
      #pragma unroll
      for (int i = 0; i < 4; ++i)
        #pragma unroll
        for (int j = 0; j < 4; ++j) acc[i][j] += av[i] * xvv[j];
    }
    if (ch < 1) {
      STOREQKV(cur ^ 1);
      __syncthreads();
    }
  }

  #pragma unroll
  for (int i = 0; i < 4; ++i) {
    float4 o4;
    o4.x = acc[i][0]; o4.y = acc[i][1]; o4.z = acc[i][2]; o4.w = acc[i][3];
    *(float4*)&P[(size_t)(tc + ty * 4 + i) * NP + tp + tx * 4] = o4;
  }
  #undef LOADQKV
  #undef STOREQKV
}

// ---------------------------------------------------------------------------
// Kernel 2: score GEMM; V-merge partial loads hoisted to kernel start so the
// merge tail overlaps the main GEMM. Otherwise R14-proven.
// ---------------------------------------------------------------------------
__global__ __launch_bounds__(256) void score_gemm_kernel(
    const float* __restrict__ Ppart,
    const float* __restrict__ bq, const float* __restrict__ bk,
    const float* __restrict__ bv,
    float* __restrict__ scores, float* __restrict__ Vt)
{
  const int tile = blockIdx.x;          // 16 = 4x4 tiles of 64x64
  const int bh   = blockIdx.y;          // 16
  const int tn = (tile >> 2) * 64;
  const int tm = (tile & 3) * 64;
  const int b = bh >> 2, h = bh & 3;
  const int tid = threadIdx.x;

  #define PBUF(KS, MAT) (Ppart + ((size_t)(((KS) * 3 + (MAT)) * 4 + b)) * 65536)

  // ---- hoisted V-merge loads (independent of Q/K staging) ------------------
  const int dV = tid >> 2;
  const int mg = tid & 3;
  const int cV = dV * 4 + h;
  const float bvb = bv[cV];
  const float4 pv0 = *(const float4*)&PBUF(0, 2)[(size_t)cV * NP + tile * 16 + mg * 4];
  const float4 pv1 = *(const float4*)&PBUF(1, 2)[(size_t)cV * NP + tile * 16 + mg * 4];
  const float4 pv2 = *(const float4*)&PBUF(2, 2)[(size_t)cV * NP + tile * 16 + mg * 4];
  const float4 pv3 = *(const float4*)&PBUF(3, 2)[(size_t)cV * NP + tile * 16 + mg * 4];

  __shared__ float Qs[64][68];   // [d][n]
  __shared__ float Ks[64][68];   // [d][m]
  __shared__ float Vs[16][68];   // V-merge transpose tile [m][d]

  #pragma unroll
  for (int pass = 0; pass < 4; ++pass) {
    const int u  = tid + pass * 256;
    const int pg = u & 15;
    const int d  = u >> 4;
    const int c  = d * 4 + h;
    const float bqv = bq[c], bkv = bk[c];
    float qx = bqv, qy = bqv, qz = bqv, qw = bqv;
    float kx = bkv, ky = bkv, kz = bkv, kw = bkv;
    #pragma unroll
    for (int ksI = 0; ksI < 4; ++ksI) {
      const float4 q = *(const float4*)&PBUF(ksI, 0)[(size_t)c * NP + tn + pg * 4];
      const float4 k = *(const float4*)&PBUF(ksI, 1)[(size_t)c * NP + tm + pg * 4];
      qx += q.x; qy += q.y; qz += q.z; qw += q.w;
      kx += k.x; ky += k.y; kz += k.z; kw += k.w;
    }
    Qs[d][pg*4+0] = qx; Qs[d][pg*4+1] = qy;
    Qs[d][pg*4+2] = qz; Qs[d][pg*4+3] = qw;
    Ks[d][pg*4+0] = kx; Ks[d][pg*4+1] = ky;
    Ks[d][pg*4+2] = kz; Ks[d][pg*4+3] = kw;
  }
  __syncthreads();

  const int ty = tid >> 4, tx = tid & 15;
  float acc[4][4];
  #pragma unroll
  for (int i = 0; i < 4; ++i)
    #pragma unroll
    for (int j = 0; j < 4; ++j) acc[i][j] = 0.f;

  #pragma unroll 4
  for (int d = 0; d < DH; ++d) {
    const float4 a  = *(const float4*)&Qs[d][ty * 4];
    const float4 bvv4 = *(const float4*)&Ks[d][tx * 4];
    const float av[4]  = {a.x, a.y, a.z, a.w};
    const float bvv[4] = {bvv4.x, bvv4.y, bvv4.z, bvv4.w};
    #pragma unroll
    for (int i = 0; i < 4; ++i)
      #pragma unroll
      for (int j = 0; j < 4; ++j) acc[i][j] += av[i] * bvv[j];
  }

  float* srow = scores + ((size_t)bh * NP + tn) * NP + tm;
  #pragma unroll
  for (int i = 0; i < 4; ++i) {
    float4 o4;
    o4.x = acc[i][0] * 0.125f; o4.y = acc[i][1] * 0.125f;
    o4.z = acc[i][2] * 0.125f; o4.w = acc[i][3] * 0.125f;
    *(float4*)&srow[(size_t)(ty * 4 + i) * NP + tx * 4] = o4;
  }

  // ---- V-merge writeout (loads already in registers) -----------------------
  Vs[mg*4+0][dV] = pv0.x + pv1.x + pv2.x + pv3.x + bvb;
  Vs[mg*4+1][dV] = pv0.y + pv1.y + pv2.y + pv3.y + bvb;
  Vs[mg*4+2][dV] = pv0.z + pv1.z + pv2.z + pv3.z + bvb;
  Vs[mg*4+3][dV] = pv0.w + pv1.w + pv2.w + pv3.w + bvb;
  __syncthreads();
  {
    const int mrow = tid >> 4;
    const int dg   = tid & 15;
    const float4 o = *(const float4*)&Vs[mrow][dg * 4];
    *(float4*)&Vt[((size_t)bh * NP + tile * 16 + mrow) * DH + dg * 4] = o;
  }
  #undef PBUF
}

// ---------------------------------------------------------------------------
// Kernel 3: ballot-radix top-k + prefetch-4 gather. V-prefetch hoisted BEFORE
// the angle phase (independent of ang); src_pos loaded at entry.
// ---------------------------------------------------------------------------
__global__ __launch_bounds__(256) void attn_topk_kernel(
    const float* __restrict__ scores, const float* __restrict__ Vt,
    const float* __restrict__ x_pos, const float* __restrict__ src_pos,
    const float* __restrict__ lrf,
    const int* __restrict__ kptr,
    float* __restrict__ O)
{
  const int tid  = threadIdx.x;
  const int wid  = tid >> 6;
  const int lane = tid & 63;
  const int bidx = blockIdx.x;                      // 0..1023
  const int rb   = (bidx & 7) * 128 + (bidx >> 3);  // bijective XCD swizzle
  const int row  = rb * 4 + wid;
  const int n    = row & (NP - 1);
  const int bh   = row >> 8;
  const int b    = bh >> 2;
  const int h    = bh & 3;

  int kk = *kptr;
  if (kk > 64) kk = 64;
  if (kk < 1) kk = 1;

  // early loads: src_pos for this row's n (used in angle phase)
  const float* spp = src_pos + ((size_t)b * NP + n) * 3;
  const float sp0 = spp[0], sp1 = spp[1], sp2 = spp[2];

  __shared__ float  eslot[4][64];
  __shared__ int    msel[4][64];
  __shared__ float4 ang[4][64];
  __shared__ float  otile[4][64];

  const float4 s4 = *(const float4*)&scores[(size_t)row * NP + lane * 4];
  float s[4] = { s4.x, s4.y, s4.z, s4.w };
  u32 u[4], lowv[4];
  #pragma unroll
  for (int r = 0; r < 4; ++r) {
    u32 bb = __float_as_uint(s[r]);
    u[r] = (bb & 0x80000000u) ? ~bb : (bb | 0x80000000u);
    lowv[r] = (u32)(255 - (lane * 4 + r));
  }

  // phase 1: T = value-bits of kth largest
  u32 T = 0u;
  #pragma unroll
  for (int bit = 31; bit >= 0; --bit) {
    const u32 cand = T | (1u << bit);
    int c = 0;
    #pragma unroll
    for (int r = 0; r < 4; ++r) c += __popcll(__ballot(u[r] >= cand));
    if (c >= kk) T = cand;
  }
  int c_gt = 0;
  #pragma unroll
  for (int r = 0; r < 4; ++r) c_gt += __popcll(__ballot(u[r] > T));

  // phase 2: tie-break threshold on low bits (255-m)
  u32 Lo = 0u;
  #pragma unroll
  for (int bit = 7; bit >= 0; --bit) {
    const u32 cand = Lo | (1u << bit);
    int c = c_gt;
    #pragma unroll
    for (int r = 0; r < 4; ++r)
      c += __popcll(__ballot((u[r] == T) && (lowv[r] >= cand)));
    if (c >= kk) Lo = cand;
  }

  // membership, e-values, Z
  const float sT = __uint_as_float((T & 0x80000000u) ? (T & 0x7fffffffu) : ~T);
  bool sel[4]; float e[4]; u64 selm[4];
  #pragma unroll
  for (int r = 0; r < 4; ++r) {
    sel[r] = (u[r] > T) || ((u[r] == T) && (lowv[r] >= Lo));
    e[r] = sel[r] ? __expf(s[r] - sT) : 0.f;
    selm[r] = __ballot(sel[r]);
  }
  float z = e[0] + e[1] + e[2] + e[3];
  #pragma unroll
  for (int off = 32; off; off >>= 1) z += __shfl_xor(z, off);

  // compaction
  const u64 lt = (1ull << lane) - 1ull;
  int base = 0;
  #pragma unroll
  for (int r = 0; r < 4; ++r) {
    if (sel[r]) {
      const int slot = base + __popcll(selm[r] & lt);
      eslot[wid][slot] = e[r];
      msel[wid][slot]  = lane * 4 + r;
    }
    base += __popcll(selm[r]);
  }

  // ---- V prefetch (depends only on msel) -- issued BEFORE angle phase so
  // the ~250cy L2 round overlaps the angle load chain -------------------------
  const float* vbase = Vt + (size_t)bh * NP * DH;
  const bool useA = ((lane & 3) < 2);
  const bool odd  = (lane & 1);
  const int  ev   = lane & ~1;
  float2 v0, v1, v2, v3;
  if (kk >= 4) {
    const int a0 = msel[wid][0], a1 = msel[wid][1];
    const int a2 = msel[wid][2], a3 = msel[wid][3];
    v0 = *(const float2*)(vbase + (size_t)a0 * DH + ev);
    v1 = *(const float2*)(vbase + (size_t)a1 * DH + ev);
    v2 = *(const float2*)(vbase + (size_t)a2 * DH + ev);
    v3 = *(const float2*)(vbase + (size_t)a3 * DH + ev);
  }

  // lane j: rotary-angle coefficients for slot j (algebraic)
  if (lane < kk) {
    const float ej = eslot[wid][lane];
    const int   mj = msel[wid][lane];
    const float p = ej / z;
    const float* xp = x_pos + ((size_t)b * NP + mj) * 3;
    const float* L  = lrf   + ((size_t)b * NP + mj) * 9;
    const float r0 = xp[0] - sp0, r1 = xp[1] - sp1, r2v = xp[2] - sp2;
    const float px = L[0]*r0 + L[3]*r1 + L[6]*r2v;   // lrf^T r
    const float py = L[1]*r0 + L[4]*r1 + L[7]*r2v;
    const float pz = L[2]*r0 + L[5]*r1 + L[8]*r2v;
    const float r2 = px*px + py*py;
    const float inv2 = (r2 > 0.f) ? rsqrtf(r2) : 0.f;
    const float ca = (r2 > 0.f) ? px * inv2 : 1.f;
    const float sa = py * inv2;
    const float r2d = r2 * inv2;
    const float r3 = r2 + pz * pz;
    const float inv3 = (r3 > 0.f) ? rsqrtf(r3) : 0.f;
    const float cph = (r3 > 0.f) ? r2d * inv3 : 1.f;
    const float sph = pz * inv3;
    ang[wid][lane] = make_float4(p * ca, p * sa, p * cph, p * sph);
  }

  // gather: 2-stage software pipeline (prefetch next 4 V-float2s)
  float acc = 0.f;

  #define ACCSTEP(V2, A4) {                                                   \
    const float vm  = odd ? (V2).y :  (V2).x;                                 \
    const float dsc = odd ? (V2).x : -(V2).y;                                 \
    acc += vm  * (useA ? (A4).x : (A4).z)                                     \
         + dsc * (useA ? (A4).y : (A4).w); }

  int j = 0;
  for (; j + 8 <= kk; j += 4) {
    const int n0 = msel[wid][j+4], n1 = msel[wid][j+5];
    const int n2 = msel[wid][j+6], n3 = msel[wid][j+7];
    const float2 w0 = *(const float2*)(vbase + (size_t)n0 * DH + ev);
    const float2 w1 = *(const float2*)(vbase + (size_t)n1 * DH + ev);
    const float2 w2 = *(const float2*)(vbase + (size_t)n2 * DH + ev);
    const float2 w3 = *(const float2*)(vbase + (size_t)n3 * DH + ev);
    const float4 A0 = ang[wid][j],   A1 = ang[wid][j+1];
    const float4 A2 = ang[wid][j+2], A3 = ang[wid][j+3];
    ACCSTEP(v0, A0); ACCSTEP(v1, A1); ACCSTEP(v2, A2); ACCSTEP(v3, A3);
    v0 = w0; v1 = w1; v2 = w2; v3 = w3;
  }
  if (j + 4 <= kk) {
    const float4 A0 = ang[wid][j],   A1 = ang[wid][j+1];
    const float4 A2 = ang[wid][j+2], A3 = ang[wid][j+3];
    ACCSTEP(v0, A0); ACCSTEP(v1, A1); ACCSTEP(v2, A2); ACCSTEP(v3, A3);
    j += 4;
  }
  for (; j < kk; ++j) {
    const int m = msel[wid][j];
    const float2 vv = *(const float2*)(vbase + (size_t)m * DH + ev);
    const float4 A  = ang[wid][j];
    ACCSTEP(vv, A);
  }
  #undef ACCSTEP

  otile[wid][lane] = acc;
  __syncthreads();
  if (wid == 0) {
    float4 o4;
    o4.x = otile[0][lane]; o4.y = otile[1][lane];
    o4.z = otile[2][lane]; o4.w = otile[3][lane];
    const int c = (lane << 2) | h;
    const int n0 = (rb * 4) & (NP - 1);
    *(float4*)&O[((size_t)b * DM + c) * NP + n0] = o4;
  }
}

// ---------------------------------------------------------------------------
// Kernel 4: final projection partials, split-K x4. 256 blocks. (R14-proven)
// ---------------------------------------------------------------------------
__global__ __launch_bounds__(256) void final_part_kernel(
    const float* __restrict__ O, const float* __restrict__ Wm,
    float* __restrict__ Pf)
{
  const int tile = blockIdx.x;          // 16 = 4x4 of 64x64
  const int ks   = blockIdx.y;          // 4 K-slices of 64
  const int b    = blockIdx.z;
  const int tc = (tile >> 2) * 64;
  const int tp = (tile & 3) * 64;
  const float* X = O + (size_t)b * DM * NP;
  float* P = Pf + (size_t)ks * (DM * NP * 4) + (size_t)b * DM * NP;

  __shared__ float Ws[2][32][64];
  __shared__ float Xs[2][32][64];
  const int tid = threadIdx.x;
  const int ty = tid >> 4, tx = tid & 15;
  const int c0 = tid >> 3;
  const int k4 = tid & 7;
  const int pX = tid & 15;
  const int kX = tid >> 4;
  const int kbase = ks * 64;

  float4 wA, wB, xA, xB;
  #define LOADF(K0)                                                            \
    wA = *(const float4*)&Wm[(size_t)(tc + c0)      * DM + (K0) + k4 * 4];     \
    wB = *(const float4*)&Wm[(size_t)(tc + c0 + 32) * DM + (K0) + k4 * 4];     \
    xA = *(const float4*)&X[(size_t)((K0) + kX)      * NP + tp + pX * 4];      \
    xB = *(const float4*)&X[(size_t)((K0) + kX + 16) * NP + tp + pX * 4];

  #define STOREF(BUF)                                                          \
    Ws[BUF][k4*4+0][c0] = wA.x; Ws[BUF][k4*4+1][c0] = wA.y;                    \
    Ws[BUF][k4*4+2][c0] = wA.z; Ws[BUF][k4*4+3][c0] = wA.w;                    \
    Ws[BUF][k4*4+0][c0+32] = wB.x; Ws[BUF][k4*4+1][c0+32] = wB.y;              \
    Ws[BUF][k4*4+2][c0+32] = wB.z; Ws[BUF][k4*4+3][c0+32] = wB.w;              \
    *(float4*)&Xs[BUF][kX][pX*4]      = xA;                                    \
    *(float4*)&Xs[BUF][kX+16][pX*4]   = xB;

  LOADF(kbase);
  STOREF(0);
  __syncthreads();

  float acc[4][4];
  #pragma unroll
  for (int i = 0; i < 4; ++i)
    #pragma unroll
    for (int j = 0; j < 4; ++j) acc[i][j] = 0.f;

  for (int ch = 0; ch < 2; ++ch) {          // K = 64 per block
    const int cur = ch & 1;
    if (ch < 1) { LOADF(kbase + 32); }
    #pragma unroll
    for (int kk = 0; kk < 32; ++kk) {
      float4 a = *(const float4*)&Ws[cur][kk][ty * 4];
      float4 xv = *(const float4*)&Xs[cur][kk][tx * 4];
      float av[4] = {a.x, a.y, a.z, a.w};
      float xvv[4] = {xv.x, xv.y, xv.z, xv.w};
      #pragma unroll
      for (int i = 0; i < 4; ++i)
        #pragma unroll
        for (int j = 0; j < 4; ++j) acc[i][j] += av[i] * xvv[j];
    }
    if (ch < 1) {
      STOREF(cur ^ 1);
      __syncthreads();
    }
  }

  #pragma unroll
  for (int i = 0; i < 4; ++i) {
    float4 o4;
    o4.x = acc[i][0]; o4.y = acc[i][1]; o4.z = acc[i][2]; o4.w = acc[i][3];
    *(float4*)&P[(size_t)(tc + ty * 4 + i) * NP + tp + tx * 4] = o4;
  }
  #undef LOADF
  #undef STOREF
}

// ---------------------------------------------------------------------------
// Kernel 5: merge final partials + bias -> out. (R12-proven)
// ---------------------------------------------------------------------------
__global__ __launch_bounds__(256) void final_merge_kernel(
    const float* __restrict__ Pf, const float* __restrict__ bm,
    float* __restrict__ out)
{
  const int u = blockIdx.x * 256 + threadIdx.x;   // 65536 float4 units
  const int c = (u >> 6) & 255;
  const float bb = bm[c];
  const size_t stride = (size_t)DM * NP * 4 / 4;
  const float4* P4 = (const float4*)Pf;
  float4 a = P4[u];
  float4 b2 = P4[u + stride];
  float4 c2 = P4[u + 2 * stride];
  float4 d2 = P4[u + 3 * stride];
  float4 o;
  o.x = a.x + b2.x + c2.x + d2.x + bb;
  o.y = a.y + b2.y + c2.y + d2.y + bb;
  o.z = a.z + b2.z + c2.z + d2.z + bb;
  o.w = a.w + b2.w + c2.w + d2.w + bb;
  ((float4*)out)[u] = o;
}

// ---------------------------------------------------------------------------
extern "C" void kernel_launch(void* const* d_in, const int* in_sizes, int n_in,
                              void* d_out, int out_size, void* d_ws, size_t ws_size,
                              hipStream_t stream)
{
  const float* x       = (const float*)d_in[0];
  const float* source  = (const float*)d_in[1];
  const float* x_pos   = (const float*)d_in[2];
  const float* src_pos = (const float*)d_in[3];
  const float* lrf     = (const float*)d_in[4];
  const float* Wq = (const float*)d_in[5];
  const float* bq = (const float*)d_in[6];
  const float* Wk = (const float*)d_in[7];
  const float* bk = (const float*)d_in[8];
  const float* Wv = (const float*)d_in[9];
  const float* bv = (const float*)d_in[10];
  const float* Wm = (const float*)d_in[11];
  const float* bm = (const float*)d_in[12];
  const int* kptr = (const int*)d_in[13];
  float* out = (float*)d_out;

  // workspace layout (floats)
  float* ws = (float*)d_ws;
  float* Ppart  = ws;                     // [4ks][3mat][4b][256][256] = 3145728
  float* scores = Ppart + 3145728;        // [16][256][256] = 1048576
  float* Vt     = scores + 1048576;       // [16][256][64]  = 262144
  float* O      = Vt + 262144;            // [4][256][256]  = 262144
  float* Pf     = O + 262144;             // [4ks][4b][256][256] = 1048576
  // total ~23 MB

  qkv_part_kernel<<<dim3(16, 3, 16), 256, 0, stream>>>(
      x, source, Wq, Wk, Wv, Ppart);
  score_gemm_kernel<<<dim3(16, 16), 256, 0, stream>>>(
      Ppart, bq, bk, bv, scores, Vt);
  attn_topk_kernel<<<dim3(1024), 256, 0, stream>>>(
      scores, Vt, x_pos, src_pos, lrf, kptr, O);
  final_part_kernel<<<dim3(16, 4, 4), 256, 0, stream>>>(
      O, Wm, Pf);
  final_merge_kernel<<<dim3(256), 256, 0, stream>>>(
      Pf, bm, out);
}